// Round 1
// baseline (10801.776 us; speedup 1.0000x reference)
//
#include <hip/hip_runtime.h>

#define DIM 64

// ---------------------------------------------------------------------------
// h[r][c] = sum_k X[r][k] * W[c][k]   (X: rows x 64, W: 64x64 row-major)
// Thread-per-row. Row held in VGPRs (16 x float4). W read with wave-uniform
// indices -> scalar loads (s_load_dwordx16), overlapping the v_fma stream.
// ---------------------------------------------------------------------------
__global__ __launch_bounds__(256) void fc_rows(const float* __restrict__ X,
                                               const float* __restrict__ W,
                                               float* __restrict__ Y,
                                               int nrows) {
    int r = blockIdx.x * blockDim.x + threadIdx.x;
    if (r >= nrows) return;
    const float* x = X + (size_t)r * DIM;
    float4 xv[16];
#pragma unroll
    for (int i = 0; i < 16; ++i)
        xv[i] = reinterpret_cast<const float4*>(x)[i];
    float* y = Y + (size_t)r * DIM;
#pragma unroll 1
    for (int c0 = 0; c0 < DIM; c0 += 4) {
        float out[4];
#pragma unroll
        for (int j = 0; j < 4; ++j) {
            const float* w = W + (size_t)(c0 + j) * DIM;  // uniform address
            float p0 = 0.f, p1 = 0.f, p2 = 0.f, p3 = 0.f;
#pragma unroll
            for (int k = 0; k < 16; ++k) {
                float4 xx = xv[k];
                p0 += xx.x * w[4 * k + 0];
                p1 += xx.y * w[4 * k + 1];
                p2 += xx.z * w[4 * k + 2];
                p3 += xx.w * w[4 * k + 3];
            }
            out[j] = (p0 + p1) + (p2 + p3);
        }
        *reinterpret_cast<float4*>(y + c0) =
            make_float4(out[0], out[1], out[2], out[3]);
    }
}

// ---------------------------------------------------------------------------
// Per edge e: eh[c] = sum_k edge_h[e][k]*W_fcr[c][k]; ex = exp(eh)
//   num[dst][c] += ex * (h[src][c] + eh[c]);  den[dst][c] += ex
// (max-subtraction omitted: alpha is shift-invariant and eh ~ N(0,1))
// ---------------------------------------------------------------------------
__global__ __launch_bounds__(256) void edge_scatter(
    const float* __restrict__ EH, const int* __restrict__ src,
    const int* __restrict__ dst, const float* __restrict__ Wr,
    const float* __restrict__ H, float* __restrict__ num,
    float* __restrict__ den, int E) {
    int e = blockIdx.x * blockDim.x + threadIdx.x;
    if (e >= E) return;
    const float* x = EH + (size_t)e * DIM;
    float4 xv[16];
#pragma unroll
    for (int i = 0; i < 16; ++i)
        xv[i] = reinterpret_cast<const float4*>(x)[i];
    int s = src[e];
    int d = dst[e];
    const float* hs = H + (size_t)s * DIM;
    float* nrow = num + (size_t)d * DIM;
    float* drow = den + (size_t)d * DIM;
#pragma unroll 1
    for (int c0 = 0; c0 < DIM; c0 += 4) {
        float eh[4];
#pragma unroll
        for (int j = 0; j < 4; ++j) {
            const float* w = Wr + (size_t)(c0 + j) * DIM;  // uniform address
            float p0 = 0.f, p1 = 0.f, p2 = 0.f, p3 = 0.f;
#pragma unroll
            for (int k = 0; k < 16; ++k) {
                float4 xx = xv[k];
                p0 += xx.x * w[4 * k + 0];
                p1 += xx.y * w[4 * k + 1];
                p2 += xx.z * w[4 * k + 2];
                p3 += xx.w * w[4 * k + 3];
            }
            eh[j] = (p0 + p1) + (p2 + p3);
        }
        float4 z = *reinterpret_cast<const float4*>(hs + c0);
        float zz[4] = {z.x, z.y, z.z, z.w};
#pragma unroll
        for (int j = 0; j < 4; ++j) {
            float ex = __expf(eh[j]);
            unsafeAtomicAdd(nrow + c0 + j, ex * (zz[j] + eh[j]));
            unsafeAtomicAdd(drow + c0 + j, ex);
        }
    }
}

// ---------------------------------------------------------------------------
// out[n][c] = relu( den>0 ? num/den + sum_k h[n][k]*loop_W[k][c] : h[n][c] )
// k-outer accumulation: acc[64] in registers (all indices compile-time).
// num aliases out (d_out used as scratch) - read before write, same thread.
// ---------------------------------------------------------------------------
__global__ __launch_bounds__(256) void finalize(
    const float* __restrict__ H, const float* __restrict__ LW,
    const float* __restrict__ num, const float* __restrict__ den,
    float* __restrict__ out, int N) {
    int n = blockIdx.x * blockDim.x + threadIdx.x;
    if (n >= N) return;
    const float* hrow = H + (size_t)n * DIM;
    float acc[DIM];
#pragma unroll
    for (int c = 0; c < DIM; ++c) acc[c] = 0.f;
#pragma unroll 1
    for (int k0 = 0; k0 < 16; ++k0) {
        float4 hk = reinterpret_cast<const float4*>(hrow)[k0];
        const float* w = LW + (size_t)k0 * 4 * DIM;  // uniform address
#pragma unroll
        for (int c = 0; c < DIM; ++c) {
            float a = acc[c];
            a += hk.x * w[c];
            a += hk.y * w[DIM + c];
            a += hk.z * w[2 * DIM + c];
            a += hk.w * w[3 * DIM + c];
            acc[c] = a;
        }
    }
    const float* nrow = num + (size_t)n * DIM;
    const float* drow = den + (size_t)n * DIM;
    float* orow = out + (size_t)n * DIM;
#pragma unroll
    for (int c0 = 0; c0 < DIM; c0 += 4) {
        float4 nv = *reinterpret_cast<const float4*>(nrow + c0);
        float4 dv = *reinterpret_cast<const float4*>(drow + c0);
        float4 hv = *reinterpret_cast<const float4*>(hrow + c0);
        float4 o;
        o.x = dv.x > 0.f ? nv.x / dv.x + acc[c0 + 0] : hv.x;
        o.y = dv.y > 0.f ? nv.y / dv.y + acc[c0 + 1] : hv.y;
        o.z = dv.z > 0.f ? nv.z / dv.z + acc[c0 + 2] : hv.z;
        o.w = dv.w > 0.f ? nv.w / dv.w + acc[c0 + 3] : hv.w;
        o.x = fmaxf(o.x, 0.f);
        o.y = fmaxf(o.y, 0.f);
        o.z = fmaxf(o.z, 0.f);
        o.w = fmaxf(o.w, 0.f);
        *reinterpret_cast<float4*>(orow + c0) = o;
    }
}

extern "C" void kernel_launch(void* const* d_in, const int* in_sizes, int n_in,
                              void* d_out, int out_size, void* d_ws,
                              size_t ws_size, hipStream_t stream) {
    const float* node_h = (const float*)d_in[0];
    const float* edge_h = (const float*)d_in[1];
    const int* src = (const int*)d_in[2];
    const int* dst = (const int*)d_in[3];
    const float* W_fc = (const float*)d_in[4];
    const float* W_fcr = (const float*)d_in[5];
    const float* loop_W = (const float*)d_in[6];

    const int N = in_sizes[0] / DIM;
    const int E = in_sizes[1] / DIM;

    float* out = (float*)d_out;
    float* h = (float*)d_ws;             // N*64 floats
    float* den = h + (size_t)N * DIM;    // N*64 floats
    float* num = out;                    // alias d_out as num scratch

    hipMemsetAsync(num, 0, (size_t)N * DIM * sizeof(float), stream);
    hipMemsetAsync(den, 0, (size_t)N * DIM * sizeof(float), stream);

    fc_rows<<<(N + 255) / 256, 256, 0, stream>>>(node_h, W_fc, h, N);
    edge_scatter<<<(E + 255) / 256, 256, 0, stream>>>(edge_h, src, dst, W_fcr,
                                                      h, num, den, E);
    finalize<<<(N + 255) / 256, 256, 0, stream>>>(h, loop_W, num, den, out, N);
}

// Round 2
// 1474.193 us; speedup vs baseline: 7.3272x; 7.3272x over previous
//
#include <hip/hip_runtime.h>

#define DIM 64

// ---------------------------------------------------------------------------
// h[r][c] = sum_k X[r][k] * W[c][k]   (X: rows x 64, W: 64x64 row-major)
// Thread-per-row, W via wave-uniform addresses -> scalar loads.
// ---------------------------------------------------------------------------
__global__ __launch_bounds__(256) void fc_rows(const float* __restrict__ X,
                                               const float* __restrict__ W,
                                               float* __restrict__ Y,
                                               int nrows) {
    int r = blockIdx.x * blockDim.x + threadIdx.x;
    if (r >= nrows) return;
    const float* x = X + (size_t)r * DIM;
    float4 xv[16];
#pragma unroll
    for (int i = 0; i < 16; ++i)
        xv[i] = reinterpret_cast<const float4*>(x)[i];
    float* y = Y + (size_t)r * DIM;
#pragma unroll 1
    for (int c0 = 0; c0 < DIM; c0 += 4) {
        float out[4];
#pragma unroll
        for (int j = 0; j < 4; ++j) {
            const float* w = W + (size_t)(c0 + j) * DIM;  // uniform address
            float p0 = 0.f, p1 = 0.f, p2 = 0.f, p3 = 0.f;
#pragma unroll
            for (int k = 0; k < 16; ++k) {
                float4 xx = xv[k];
                p0 += xx.x * w[4 * k + 0];
                p1 += xx.y * w[4 * k + 1];
                p2 += xx.z * w[4 * k + 2];
                p3 += xx.w * w[4 * k + 3];
            }
            out[j] = (p0 + p1) + (p2 + p3);
        }
        *reinterpret_cast<float4*>(y + c0) =
            make_float4(out[0], out[1], out[2], out[3]);
    }
}

// ---------------------------------------------------------------------------
// deg[dst[e]]++  (int atomics, 400KB L2-resident)
// ---------------------------------------------------------------------------
__global__ __launch_bounds__(256) void hist(const int* __restrict__ dst,
                                            int* __restrict__ deg, int E) {
    int e = blockIdx.x * blockDim.x + threadIdx.x;
    if (e < E) atomicAdd(&deg[dst[e]], 1);
}

// ---------------------------------------------------------------------------
// Single-block exclusive scan: offsets[i] = sum_{j<i} deg[j]; cursor = copy.
// ---------------------------------------------------------------------------
#define SCAN_T 1024
__global__ __launch_bounds__(SCAN_T) void scan_offsets(
    const int* __restrict__ deg, int* __restrict__ offsets,
    int* __restrict__ cursor, int N) {
    __shared__ int buf[2][SCAN_T];
    int t = threadIdx.x;
    int carry = 0;
    int nch = (N + SCAN_T - 1) / SCAN_T;
    for (int ch = 0; ch < nch; ++ch) {
        int i = ch * SCAN_T + t;
        int v = (i < N) ? deg[i] : 0;
        int pa = 0;
        buf[0][t] = v;
        __syncthreads();
        for (int off = 1; off < SCAN_T; off <<= 1) {
            int nv = buf[pa][t] + ((t >= off) ? buf[pa][t - off] : 0);
            __syncthreads();
            buf[pa ^ 1][t] = nv;
            __syncthreads();
            pa ^= 1;
        }
        int incl = buf[pa][t];
        int total = buf[pa][SCAN_T - 1];
        __syncthreads();  // everyone read buf before next chunk overwrites
        if (i < N) {
            int ex = carry + incl - v;
            offsets[i] = ex;
            cursor[i] = ex;
        }
        carry += total;
    }
}

// ---------------------------------------------------------------------------
// CSR build: slot p = cursor[dst]++ ; perm[p] = e ; srcs[p] = src[e]
// ---------------------------------------------------------------------------
__global__ __launch_bounds__(256) void scatter(const int* __restrict__ src,
                                               const int* __restrict__ dst,
                                               int* __restrict__ cursor,
                                               int* __restrict__ perm,
                                               int* __restrict__ srcs, int E) {
    int e = blockIdx.x * blockDim.x + threadIdx.x;
    if (e < E) {
        int d = dst[e];
        int p = atomicAdd(&cursor[d], 1);
        perm[p] = e;
        srcs[p] = src[e];
    }
}

// ---------------------------------------------------------------------------
// Wave per node, lane = channel c.
// Per edge: eh[c] = dot(edge_h[e], W_fcr[c]) via LDS-broadcast of edge row
// against per-lane W row (64 VGPRs); ex=exp(eh); num += ex*(h[src][c]+eh);
// den += ex. Epilogue: relu(num/den + (h[n] @ loop_W)[c]) or relu(h[n][c]).
// No max-subtraction: softmax is shift-invariant, eh ~ N(0,1).
// ---------------------------------------------------------------------------
__global__ __launch_bounds__(256) void reduce_nodes(
    const float* __restrict__ EH, const float* __restrict__ H,
    const float* __restrict__ Wr, const float* __restrict__ LW,
    const int* __restrict__ offsets, const int* __restrict__ deg,
    const int* __restrict__ perm, const int* __restrict__ srcs,
    float* __restrict__ out, int N) {
    __shared__ float xrow[4][DIM];
    int wid = threadIdx.x >> 6;
    int lane = threadIdx.x & 63;
    int n = blockIdx.x * 4 + wid;
    if (n >= N) return;
    float* myx = xrow[wid];

    // per-lane W_fcr row (channel = lane): 64 VGPRs
    float wr[DIM];
#pragma unroll
    for (int k4 = 0; k4 < 16; ++k4) {
        float4 w = *reinterpret_cast<const float4*>(Wr + (size_t)lane * DIM + 4 * k4);
        wr[4 * k4 + 0] = w.x;
        wr[4 * k4 + 1] = w.y;
        wr[4 * k4 + 2] = w.z;
        wr[4 * k4 + 3] = w.w;
    }

    int start = offsets[n];
    int cnt = deg[n];
    float num = 0.f, den = 0.f;

    float xv_nxt = 0.f, z_nxt = 0.f;
    if (cnt > 0) {
        int e0 = perm[start];
        int s0 = srcs[start];
        xv_nxt = EH[(size_t)e0 * DIM + lane];
        z_nxt = H[(size_t)s0 * DIM + lane];
    }
#pragma unroll 1
    for (int j = 0; j < cnt; ++j) {
        float xv = xv_nxt, z = z_nxt;
        myx[lane] = xv;
        if (j + 1 < cnt) {  // prefetch next edge row + src row
            int e2 = perm[start + j + 1];
            int s2 = srcs[start + j + 1];
            xv_nxt = EH[(size_t)e2 * DIM + lane];
            z_nxt = H[(size_t)s2 * DIM + lane];
        }
        asm volatile("s_waitcnt lgkmcnt(0)" ::: "memory");
        float eh = 0.f;
#pragma unroll
        for (int k4 = 0; k4 < 16; ++k4) {
            float4 x4 = *reinterpret_cast<const float4*>(myx + 4 * k4);  // broadcast
            eh += x4.x * wr[4 * k4 + 0];
            eh += x4.y * wr[4 * k4 + 1];
            eh += x4.z * wr[4 * k4 + 2];
            eh += x4.w * wr[4 * k4 + 3];
        }
        float ex = __expf(eh);
        num += ex * (z + eh);
        den += ex;
    }

    float hval = H[(size_t)n * DIM + lane];
    float res;
    if (cnt > 0) {
        myx[lane] = hval;
        asm volatile("s_waitcnt lgkmcnt(0)" ::: "memory");
        float loop = 0.f;
#pragma unroll
        for (int k4 = 0; k4 < 16; ++k4) {
            float4 x4 = *reinterpret_cast<const float4*>(myx + 4 * k4);  // broadcast
            loop += x4.x * LW[(4 * k4 + 0) * DIM + lane];  // coalesced, L1-hit
            loop += x4.y * LW[(4 * k4 + 1) * DIM + lane];
            loop += x4.z * LW[(4 * k4 + 2) * DIM + lane];
            loop += x4.w * LW[(4 * k4 + 3) * DIM + lane];
        }
        res = num / den + loop;
    } else {
        res = hval;
    }
    out[(size_t)n * DIM + lane] = fmaxf(res, 0.f);
}

extern "C" void kernel_launch(void* const* d_in, const int* in_sizes, int n_in,
                              void* d_out, int out_size, void* d_ws,
                              size_t ws_size, hipStream_t stream) {
    const float* node_h = (const float*)d_in[0];
    const float* edge_h = (const float*)d_in[1];
    const int* src = (const int*)d_in[2];
    const int* dst = (const int*)d_in[3];
    const float* W_fc = (const float*)d_in[4];
    const float* W_fcr = (const float*)d_in[5];
    const float* loop_W = (const float*)d_in[6];

    const int N = in_sizes[0] / DIM;
    const int E = in_sizes[1] / DIM;

    float* out = (float*)d_out;

    // workspace layout (~39.6 MB; proven >= 51.2 MB available in R1)
    float* h = (float*)d_ws;                  // N*64 f32
    int* deg = (int*)(h + (size_t)N * DIM);   // N
    int* offsets = deg + N;                   // N
    int* cursor = offsets + N;                // N
    int* perm = cursor + N;                   // E
    int* srcs = perm + E;                     // E

    hipMemsetAsync(deg, 0, (size_t)N * sizeof(int), stream);

    fc_rows<<<(N + 255) / 256, 256, 0, stream>>>(node_h, W_fc, h, N);
    hist<<<(E + 255) / 256, 256, 0, stream>>>(dst, deg, E);
    scan_offsets<<<1, SCAN_T, 0, stream>>>(deg, offsets, cursor, N);
    scatter<<<(E + 255) / 256, 256, 0, stream>>>(src, dst, cursor, perm, srcs, E);
    reduce_nodes<<<(N + 3) / 4, 256, 0, stream>>>(edge_h, h, W_fcr, loop_W,
                                                  offsets, deg, perm, srcs, out, N);
}